// Round 2
// baseline (228.916 us; speedup 1.0000x reference)
//
#include <hip/hip_runtime.h>
#include <hip/hip_bf16.h>

#define NN 50000
#define NE 600000
#define CAP 64              // bucket capacity per node (Poisson(12): P(deg>64) ~ e^-55)

typedef __attribute__((ext_vector_type(8))) short short8v;   // 8 bf16 = 4 VGPRs
typedef __attribute__((ext_vector_type(4))) float float4v;   // MFMA C/D
typedef __attribute__((ext_vector_type(2))) float f32x2;     // packed fp32 (v_pk_fma_f32)

// Dataset facts (pinned on HW over R3-R8): floats fp32, edges int32, out fp32.
__device__ __forceinline__ float bf2f_u(unsigned short u) {
    union { unsigned int i; float f; } v; v.i = ((unsigned int)u) << 16; return v.f;
}
__device__ __forceinline__ unsigned short f2bf_u(float f) {
    __hip_bfloat16 b = __float2bfloat16(f);
    return *reinterpret_cast<unsigned short*>(&b);
}

// ---------------------------------------------------------------------------
// prep+zero: blocks [0,128) convert fp32 W[k][n] -> bf16 Wt[n][k] (both Ws);
// blocks [128,324) zero cnt.
// ---------------------------------------------------------------------------
__global__ __launch_bounds__(256) void prep_zero(const float* __restrict__ W1,
                                                 const float* __restrict__ W2,
                                                 unsigned short* __restrict__ wt1,
                                                 unsigned short* __restrict__ wt2,
                                                 int* __restrict__ cnt) {
    int b = blockIdx.x;
    if (b < 128) {
        int t = b * 256 + threadIdx.x;             // 0..32767
        const float* src = (t < 16384) ? W1 : W2;
        unsigned short* dst = (t < 16384) ? wt1 : wt2;
        int idx = t & 16383;
        int n = idx >> 7, k = idx & 127;
        dst[idx] = f2bf_u(src[k * 128 + n]);
        return;
    }
    int g = (b - 128) * 256 + threadIdx.x;
    if (g < NN) cnt[g] = 0;
}

// ---------------------------------------------------------------------------
// Bucketed CSR fill (R18): atomicAdd on cnt gives the slot directly.
// ---------------------------------------------------------------------------
__global__ __launch_bounds__(256) void csr_fill(const int* __restrict__ ei,
                                                int* __restrict__ cnt,
                                                int* __restrict__ csrc) {
    int e = blockIdx.x * 256 + threadIdx.x;
    if (e >= NE) return;
    int s = ei[e], d = ei[NE + e];
    s = min(max(s, 0), NN - 1);
    d = min(max(d, 0), NN - 1);
    int pos = atomicAdd(&cnt[d], 1);
    if (pos < CAP) csrc[(d << 6) + pos] = s;
}

// ---------------------------------------------------------------------------
// MFMA bf16 GEMM + fused attention-logit epilogue.
// R19: als/ald reduction via LDS transpose-reduce (reusing dead Xs/WtS space
// through a union) instead of the 128-shfl butterfly — epilogue issue slots
// drop ~3x; numerics identical up to fp32 summation order.
// Row stride 196 floats (196%32=4) so the 16 reducing lanes spread banks.
// C/D layout (m97): col=ct*16+m, row=wrow+q*4+r; head=ct>>1 for H=4.
// ---------------------------------------------------------------------------
template<int H, int XF32>
__global__ __launch_bounds__(256) void gemm_fused(const void* __restrict__ X,
                                                  const unsigned short* __restrict__ Wt,
                                                  const float* __restrict__ a_src,
                                                  const float* __restrict__ a_dst,
                                                  unsigned short* __restrict__ Hout,
                                                  float* __restrict__ als,
                                                  float* __restrict__ ald, int n) {
    __shared__ union SM {
        struct { unsigned short Xs[64][136]; unsigned short WtS[128][136]; } s;
        float red[64][196];
    } sm;
    __shared__ float as_s[128], ad_s[128];
    const int tid = threadIdx.x;
    const int row0 = blockIdx.x * 64;

    if (tid < 128) { as_s[tid] = a_src[tid]; ad_s[tid] = a_dst[tid]; }
    {   // stage pre-transposed Wt: pure uint4 copies (conflict-free)
        const uint4* Wv = (const uint4*)Wt;
#pragma unroll
        for (int i = 0; i < 8; ++i) {
            int lin = tid + 256 * i;              // 0..2047
            int r = lin >> 4, c8 = lin & 15;
            *(uint4*)&sm.s.WtS[r][c8 * 8] = Wv[lin];
        }
    }
    if (XF32) {
        const float4* Xv = (const float4*)X;
#pragma unroll
        for (int i = 0; i < 8; ++i) {
            int lin = tid + 256 * i;
            int r = lin >> 5, c4 = lin & 31;
            float4 v = make_float4(0.f, 0.f, 0.f, 0.f);
            if (row0 + r < n) v = Xv[(size_t)(row0 + r) * 32 + c4];
            ushort4 o;
            o.x = f2bf_u(v.x); o.y = f2bf_u(v.y); o.z = f2bf_u(v.z); o.w = f2bf_u(v.w);
            *(ushort4*)&sm.s.Xs[r][c4 * 4] = o;
        }
    } else {
        const uint4* Xv = (const uint4*)X;
#pragma unroll
        for (int i = 0; i < 4; ++i) {
            int lin = tid + 256 * i;
            int r = lin >> 4, c8 = lin & 15;
            uint4 v = make_uint4(0u, 0u, 0u, 0u);
            if (row0 + r < n) v = Xv[(size_t)(row0 + r) * 16 + c8];
            *(uint4*)&sm.s.Xs[r][c8 * 8] = v;
        }
    }
    __syncthreads();

    const int lane = tid & 63;
    const int wrow = (tid >> 6) * 16;
    const int m = lane & 15, q = lane >> 4;

    float4v acc[8];
#pragma unroll
    for (int ct = 0; ct < 8; ++ct) acc[ct] = (float4v){0.f, 0.f, 0.f, 0.f};

#pragma unroll
    for (int kt = 0; kt < 4; ++kt) {
        short8v af = *(const short8v*)&sm.s.Xs[wrow + m][kt * 32 + q * 8];
#pragma unroll
        for (int ct = 0; ct < 8; ++ct) {
            short8v bf = *(const short8v*)&sm.s.WtS[ct * 16 + m][kt * 32 + q * 8];
            acc[ct] = __builtin_amdgcn_mfma_f32_16x16x32_bf16(af, bf, acc[ct], 0, 0, 0);
        }
    }

    // store H (bf16) — global, no LDS dependence
#pragma unroll
    for (int ct = 0; ct < 8; ++ct)
#pragma unroll
        for (int r = 0; r < 4; ++r) {
            int grow = row0 + wrow + q * 4 + r;
            if (grow < n) Hout[(size_t)grow * 128 + ct * 16 + m] = f2bf_u(acc[ct][r]);
        }

    // --- als/ald epilogue: per-thread partials -> LDS -> transpose-reduce ---
    __syncthreads();   // all waves done reading Xs/WtS; safe to overlay red
#pragma unroll
    for (int r = 0; r < 4; ++r) {
        int row = wrow + q * 4 + r;
        if (H == 4) {
            float pv[8];
#pragma unroll
            for (int hd = 0; hd < 4; ++hd) {
                float x0 = acc[2 * hd][r], x1 = acc[2 * hd + 1][r];
                pv[hd]     = x0 * as_s[hd * 32 + m] + x1 * as_s[hd * 32 + 16 + m];
                pv[4 + hd] = x0 * ad_s[hd * 32 + m] + x1 * ad_s[hd * 32 + 16 + m];
            }
            *(float4*)&sm.red[row][m * 12]     = make_float4(pv[0], pv[1], pv[2], pv[3]);
            *(float4*)&sm.red[row][m * 12 + 4] = make_float4(pv[4], pv[5], pv[6], pv[7]);
        } else {
            float ps = 0.f, pd = 0.f;
#pragma unroll
            for (int ct = 0; ct < 8; ++ct) {
                ps += acc[ct][r] * as_s[ct * 16 + m];
                pd += acc[ct][r] * ad_s[ct * 16 + m];
            }
            *(float2*)&sm.red[row][m * 12] = make_float2(ps, pd);
        }
    }
    __syncthreads();
    if (H == 4) {
        int row = tid >> 2, pr = tid & 3, s0 = pr * 2;
        float2 sum = make_float2(0.f, 0.f);
#pragma unroll
        for (int mm = 0; mm < 16; ++mm) {
            float2 v = *(const float2*)&sm.red[row][mm * 12 + s0];
            sum.x += v.x; sum.y += v.y;
        }
        int grow = row0 + row;
        if (grow < n) {
            if (pr < 2) *(float2*)&als[(size_t)grow * 4 + s0] = sum;
            else        *(float2*)&ald[(size_t)grow * 4 + (s0 - 4)] = sum;
        }
    } else {
        if (tid < 128) {
            int row = tid >> 1, s = tid & 1;
            float sum = 0.f;
#pragma unroll
            for (int mm = 0; mm < 16; ++mm) sum += sm.red[row][mm * 12 + s];
            int grow = row0 + row;
            if (grow < n) { if (s == 0) als[grow] = sum; else ald[grow] = sum; }
        }
    }
}

// ---------------------------------------------------------------------------
// Aggregate v5 (R19): kill the 4x-redundant exp. A 16-lane group covers
// 4 edges x 4 heads = 16 (edge,head) logits — one per lane (hd==(lane>>2)&3
// already). Each lane loads ONE als value + runs ONE exp chain for
// (edge=lane&3, head=own), then 4 ds_bpermute broadcast ex[k] to the group.
// Per round: loads 9->6, exp chains 4->1. Numerics bit-identical.
// FINAL=0: +bias, ELU, bf16 out. FINAL=1: +bias, fp32 out. No atomics.
// ---------------------------------------------------------------------------
template<int H, int FINAL>
__global__ __launch_bounds__(256) void aggregate(const int* __restrict__ cnt,
                                                 const int* __restrict__ csrc,
                                                 const unsigned short* __restrict__ h,
                                                 const float* __restrict__ als,
                                                 const float* __restrict__ ald,
                                                 const float* __restrict__ bias,
                                                 void* __restrict__ out) {
    int wid = (int)((blockIdx.x * 256 + threadIdx.x) >> 6);
    int lane = threadIdx.x & 63;
    if (wid >= NN) return;
    const int d = wid;
    const int g = lane >> 4;           // edge group 0..3
    const int c0 = (lane & 15) * 8;    // this lane's 8 channels
    const int hd = (H == 4) ? (c0 >> 5) : 0;   // == (lane>>2)&3 when H==4
    const float aldd = (H == 4) ? ald[(size_t)d * 4 + hd] : ald[d];

    const char* hB   = (const char*)h;
    const char* alsB = (const char*)als;
    const char* csB  = (const char*)csrc;
    const unsigned coff = (unsigned)(c0 << 1);           // byte offset of my 8ch
    const unsigned aoff = (H == 4) ? (unsigned)(hd << 2) : 0u;
    const int myk = lane & 3;                            // the edge I exp for

    f32x2 acc2[4];
#pragma unroll
    for (int i = 0; i < 4; ++i) { acc2[i].x = 0.f; acc2[i].y = 0.f; }
    float den = 0.f;

    auto expw = [&](float av) {
        float v = av + aldd;
        v = fmaxf(v, 0.2f * v);        // leaky_relu, slope<1
        return __expf(fminf(v, 60.f));
    };
    auto accum = [&](uint4 hv, float ex) {
        f32x2 exv; exv.x = ex; exv.y = ex;
#pragma unroll
        for (int i = 0; i < 4; ++i) {
            unsigned w = ((const unsigned*)&hv)[i];
            f32x2 hf;
            hf.x = __uint_as_float(w << 16);
            hf.y = __uint_as_float(w & 0xffff0000u);
            acc2[i] += exv * hf;       // ch 2i (lo), 2i+1 (hi)
        }
        den += ex;
    };

    if (g == 0) {   // self-loop handled by group 0 only
        float av = (H == 4) ? als[(size_t)d * 4 + hd] : als[d];
        uint4 hv = *(const uint4*)(hB + (((unsigned)d << 8) + coff));
        accum(hv, expw(av));
    }

    const unsigned cbase = (unsigned)d << 8;             // bucket byte base
    const int c = min(cnt[d], CAP);
    for (int j0 = 0; j0 < c; j0 += 16) {
        int jb = j0 + 4 * g;                             // my quad's first slot
        int4 iv = *(const int4*)(csB + (cbase + ((unsigned)jb << 2)));
        int idm[4];
#pragma unroll
        for (int k = 0; k < 4; ++k)
            idm[k] = min(max(((const int*)&iv)[k], 0), NN - 1);  // OOB: clamp garbage
        uint4 hv[4];
#pragma unroll
        for (int k = 0; k < 4; ++k)
            hv[k] = *(const uint4*)(hB + (((unsigned)idm[k] << 8) + coff));
        // one als load + one exp per lane: my (edge=myk, head=hd)
        float avm = (H == 4) ? *(const float*)(alsB + (((unsigned)idm[myk] << 4) + aoff))
                             : *(const float*)(alsB + ((unsigned)idm[myk] << 2));
        float em = expw(avm);
        float ex[4];
#pragma unroll
        for (int k = 0; k < 4; ++k)
            ex[k] = __shfl(em, (lane & 60) | k);         // same head quartet
#pragma unroll
        for (int k = 0; k < 4; ++k)
            accum(hv[k], (jb + k < c) ? ex[k] : 0.f);    // predicate OOB edges
    }

    // combine the 4 groups: butterfly over lanes 16, 32 apart
#pragma unroll
    for (int o = 16; o < 64; o <<= 1) {
#pragma unroll
        for (int i = 0; i < 4; ++i) {
            acc2[i].x += __shfl_xor(acc2[i].x, o);
            acc2[i].y += __shfl_xor(acc2[i].y, o);
        }
        den += __shfl_xor(den, o);
    }
    if (g != 0) return;

    const float inv = 1.f / den;
    float4 b0 = *(const float4*)&bias[c0];
    float4 b1 = *(const float4*)&bias[c0 + 4];
    float v[8];
    v[0] = acc2[0].x * inv + b0.x; v[1] = acc2[0].y * inv + b0.y;
    v[2] = acc2[1].x * inv + b0.z; v[3] = acc2[1].y * inv + b0.w;
    v[4] = acc2[2].x * inv + b1.x; v[5] = acc2[2].y * inv + b1.y;
    v[6] = acc2[3].x * inv + b1.z; v[7] = acc2[3].y * inv + b1.w;
    if (FINAL) {
        float* op = (float*)out + (size_t)d * 128 + c0;
        *(float4*)op       = make_float4(v[0], v[1], v[2], v[3]);
        *(float4*)(op + 4) = make_float4(v[4], v[5], v[6], v[7]);
    } else {
#pragma unroll
        for (int i = 0; i < 8; ++i) v[i] = v[i] > 0.f ? v[i] : expm1f(v[i]);
        unsigned int p[4];
#pragma unroll
        for (int i = 0; i < 4; ++i)
            p[i] = (unsigned int)f2bf_u(v[2 * i]) | ((unsigned int)f2bf_u(v[2 * i + 1]) << 16);
        *(uint4*)((unsigned short*)out + (size_t)d * 128 + c0) =
            make_uint4(p[0], p[1], p[2], p[3]);
    }
}

// ---------------------------------------------------------------------------
extern "C" void kernel_launch(void* const* d_in, const int* in_sizes, int n_in,
                              void* d_out, int out_size, void* d_ws, size_t ws_size,
                              hipStream_t stream) {
    const float* x      = (const float*)d_in[0];
    const int*   ei     = (const int*)d_in[1];
    const float* W1     = (const float*)d_in[2];
    const float* a_src1 = (const float*)d_in[3];
    const float* a_dst1 = (const float*)d_in[4];
    const float* b1     = (const float*)d_in[5];
    const float* W2     = (const float*)d_in[6];
    const float* a_src2 = (const float*)d_in[7];
    const float* a_dst2 = (const float*)d_in[8];
    const float* b2     = (const float*)d_in[9];

    const int N = NN;

    // Workspace: explicit BYTE offsets, every buffer 16B-aligned.
    char* base = (char*)d_ws;
    int*   cnt  = (int*)(base + 0);                       //  50000 i
    int*   csrc = (int*)(base + 200000);                  //  50000*64 i (bucketed)
    float* als  = (float*)(base + 13000000);              // 200000 f
    float* ald  = (float*)(base + 13800000);              // 200000 f
    unsigned short* h   = (unsigned short*)(base + 14600000);  // N*128 bf16
    unsigned short* x2  = (unsigned short*)(base + 27400000);  // N*128 bf16
    unsigned short* wt1 = (unsigned short*)(base + 40200000);  // 16384 bf16
    unsigned short* wt2 = (unsigned short*)(base + 40232768);  // 16384 bf16
    // total ~40.27 MB

    const int gemmGrid  = (N + 63) / 64;          // 782
    const int edgeGrid  = (NE + 255) / 256;       // 2344
    const int zeroGrid  = (N + 255) / 256;        // 196
    const int aggGrid   = (N * 64 + 255) / 256;   // 12500

    prep_zero<<<128 + zeroGrid, 256, 0, stream>>>(W1, W2, wt1, wt2, cnt);
    csr_fill<<<edgeGrid, 256, 0, stream>>>(ei, cnt, csrc);
    gemm_fused<4, 1><<<gemmGrid, 256, 0, stream>>>(x, wt1, a_src1, a_dst1, h, als, ald, N);
    aggregate<4, 0><<<aggGrid, 256, 0, stream>>>(cnt, csrc, h, als, ald, b1, x2);
    gemm_fused<1, 0><<<gemmGrid, 256, 0, stream>>>(x2, wt2, a_src2, a_dst2, h, als, ald, N);
    aggregate<1, 1><<<aggGrid, 256, 0, stream>>>(cnt, csrc, h, als, ald, b2, d_out);
}

// Round 4
// 218.200 us; speedup vs baseline: 1.0491x; 1.0491x over previous
//
#include <hip/hip_runtime.h>
#include <hip/hip_bf16.h>

#define NN 50000
#define NE 600000
#define CAP 64              // bucket capacity per node (Poisson(12): P(deg>64) ~ e^-55)

typedef __attribute__((ext_vector_type(8))) short short8v;   // 8 bf16 = 4 VGPRs
typedef __attribute__((ext_vector_type(4))) float float4v;   // MFMA C/D
typedef __attribute__((ext_vector_type(2))) float f32x2;     // packed fp32 (v_pk_fma_f32)

// Dataset facts (pinned on HW over R3-R8): floats fp32, edges int32, out fp32.
__device__ __forceinline__ float bf2f_u(unsigned short u) {
    union { unsigned int i; float f; } v; v.i = ((unsigned int)u) << 16; return v.f;
}
__device__ __forceinline__ unsigned short f2bf_u(float f) {
    __hip_bfloat16 b = __float2bfloat16(f);
    return *reinterpret_cast<unsigned short*>(&b);
}
__device__ __forceinline__ unsigned cvt_pk_bf16(float lo, float hi) {
    unsigned r;
    asm volatile("v_cvt_pk_bf16_f32 %0, %1, %2" : "=v"(r) : "v"(lo), "v"(hi));
    return r;   // D.bf16[0]=S0 (lo), D.bf16[1]=S1 (hi) — T12 primitive
}

// ---------------------------------------------------------------------------
// prep+zero: blocks [0,128) convert fp32 W[k][n] -> bf16 Wt[n][k] (both Ws);
// blocks [128,324) zero cnt.
// ---------------------------------------------------------------------------
__global__ __launch_bounds__(256) void prep_zero(const float* __restrict__ W1,
                                                 const float* __restrict__ W2,
                                                 unsigned short* __restrict__ wt1,
                                                 unsigned short* __restrict__ wt2,
                                                 int* __restrict__ cnt) {
    int b = blockIdx.x;
    if (b < 128) {
        int t = b * 256 + threadIdx.x;             // 0..32767
        const float* src = (t < 16384) ? W1 : W2;
        unsigned short* dst = (t < 16384) ? wt1 : wt2;
        int idx = t & 16383;
        int n = idx >> 7, k = idx & 127;
        dst[idx] = f2bf_u(src[k * 128 + n]);
        return;
    }
    int g = (b - 128) * 256 + threadIdx.x;
    if (g < NN) cnt[g] = 0;
}

// ---------------------------------------------------------------------------
// Bucketed CSR fill (R18): atomicAdd on cnt gives the slot directly.
// ---------------------------------------------------------------------------
__global__ __launch_bounds__(256) void csr_fill(const int* __restrict__ ei,
                                                int* __restrict__ cnt,
                                                int* __restrict__ csrc) {
    int e = blockIdx.x * 256 + threadIdx.x;
    if (e >= NE) return;
    int s = ei[e], d = ei[NE + e];
    s = min(max(s, 0), NN - 1);
    d = min(max(d, 0), NN - 1);
    int pos = atomicAdd(&cnt[d], 1);
    if (pos < CAP) csrc[(d << 6) + pos] = s;
}

// ---------------------------------------------------------------------------
// MFMA bf16 GEMM, R20: SWAPPED operands -> acc = C^T fragments. Each lane owns
// ONE row (row0+wrow+(lane&15)) and 4 contiguous cols per ct (ct*16+q*4+r).
//  - H store: 8x uint2 (16 cvt_pk) instead of 32 scalar 2-B stores
//  - als/ald: lane-local 64 fma + 2-step q-butterfly; no LDS union, no extra
//    barriers
// Validity of swap: af/bf fragments use identical per-lane addressing, so
// mfma(bf,af) = C^T with the same m97 C-layout formula.
// ---------------------------------------------------------------------------
template<int H, int XF32>
__global__ __launch_bounds__(256) void gemm_fused(const void* __restrict__ X,
                                                  const unsigned short* __restrict__ Wt,
                                                  const float* __restrict__ a_src,
                                                  const float* __restrict__ a_dst,
                                                  unsigned short* __restrict__ Hout,
                                                  float* __restrict__ als,
                                                  float* __restrict__ ald, int n) {
    __shared__ unsigned short Xs[64][136];
    __shared__ unsigned short WtS[128][136];
    __shared__ float as_s[128], ad_s[128];
    const int tid = threadIdx.x;
    const int row0 = blockIdx.x * 64;

    if (tid < 128) { as_s[tid] = a_src[tid]; ad_s[tid] = a_dst[tid]; }
    {   // stage pre-transposed Wt: pure uint4 copies (conflict-free)
        const uint4* Wv = (const uint4*)Wt;
#pragma unroll
        for (int i = 0; i < 8; ++i) {
            int lin = tid + 256 * i;              // 0..2047
            int r = lin >> 4, c8 = lin & 15;
            *(uint4*)&WtS[r][c8 * 8] = Wv[lin];
        }
    }
    if (XF32) {
        const float4* Xv = (const float4*)X;
#pragma unroll
        for (int i = 0; i < 8; ++i) {
            int lin = tid + 256 * i;
            int r = lin >> 5, c4 = lin & 31;
            float4 v = make_float4(0.f, 0.f, 0.f, 0.f);
            if (row0 + r < n) v = Xv[(size_t)(row0 + r) * 32 + c4];
            ushort4 o;
            o.x = f2bf_u(v.x); o.y = f2bf_u(v.y); o.z = f2bf_u(v.z); o.w = f2bf_u(v.w);
            *(ushort4*)&Xs[r][c4 * 4] = o;
        }
    } else {
        const uint4* Xv = (const uint4*)X;
#pragma unroll
        for (int i = 0; i < 4; ++i) {
            int lin = tid + 256 * i;
            int r = lin >> 4, c8 = lin & 15;
            uint4 v = make_uint4(0u, 0u, 0u, 0u);
            if (row0 + r < n) v = Xv[(size_t)(row0 + r) * 16 + c8];
            *(uint4*)&Xs[r][c8 * 8] = v;
        }
    }
    __syncthreads();

    const int lane = tid & 63;
    const int wrow = (tid >> 6) * 16;
    const int m = lane & 15, q = lane >> 4;

    float4v acc[8];
#pragma unroll
    for (int ct = 0; ct < 8; ++ct) acc[ct] = (float4v){0.f, 0.f, 0.f, 0.f};

#pragma unroll
    for (int kt = 0; kt < 4; ++kt) {
        short8v af = *(const short8v*)&Xs[wrow + m][kt * 32 + q * 8];
#pragma unroll
        for (int ct = 0; ct < 8; ++ct) {
            short8v bf = *(const short8v*)&WtS[ct * 16 + m][kt * 32 + q * 8];
            acc[ct] = __builtin_amdgcn_mfma_f32_16x16x32_bf16(bf, af, acc[ct], 0, 0, 0);
        }
    }
    // acc[ct][r] = H[row0+wrow+m][ct*16 + q*4 + r]

    const int grow = row0 + wrow + m;
    const bool ok = grow < n;

    // store H (bf16): one row per lane, 8x 8-byte stores
    if (ok) {
#pragma unroll
        for (int ct = 0; ct < 8; ++ct) {
            unsigned lo = cvt_pk_bf16(acc[ct][0], acc[ct][1]);
            unsigned hi = cvt_pk_bf16(acc[ct][2], acc[ct][3]);
            *(uint2*)&Hout[(size_t)grow * 128 + ct * 16 + q * 4] = make_uint2(lo, hi);
        }
    }

    // als/ald: lane-local partial dot over my 32 cols, butterfly over q
    if (H == 4) {
        float ps[4], pd[4];
#pragma unroll
        for (int hd = 0; hd < 4; ++hd) {
            ps[hd] = 0.f; pd[hd] = 0.f;
#pragma unroll
            for (int p2 = 0; p2 < 2; ++p2)
#pragma unroll
                for (int r = 0; r < 4; ++r) {
                    float xv = acc[2 * hd + p2][r];
                    int col = hd * 32 + p2 * 16 + q * 4 + r;
                    ps[hd] += xv * as_s[col];
                    pd[hd] += xv * ad_s[col];
                }
        }
#pragma unroll
        for (int o = 16; o < 64; o <<= 1)
#pragma unroll
            for (int hd = 0; hd < 4; ++hd) {
                ps[hd] += __shfl_xor(ps[hd], o);
                pd[hd] += __shfl_xor(pd[hd], o);
            }
        if (q == 0 && ok) {
            *(float4*)&als[(size_t)grow * 4] = make_float4(ps[0], ps[1], ps[2], ps[3]);
            *(float4*)&ald[(size_t)grow * 4] = make_float4(pd[0], pd[1], pd[2], pd[3]);
        }
    } else {
        float ps = 0.f, pd = 0.f;
#pragma unroll
        for (int ct = 0; ct < 8; ++ct)
#pragma unroll
            for (int r = 0; r < 4; ++r) {
                float xv = acc[ct][r];
                int col = ct * 16 + q * 4 + r;
                ps += xv * as_s[col];
                pd += xv * ad_s[col];
            }
#pragma unroll
        for (int o = 16; o < 64; o <<= 1) {
            ps += __shfl_xor(ps, o);
            pd += __shfl_xor(pd, o);
        }
        if (q == 0 && ok) { als[grow] = ps; ald[grow] = pd; }
    }
}

// ---------------------------------------------------------------------------
// Aggregate v6 (R20): TWO nodes per wave (32 lanes each, 2 edge-groups of 16).
// Wave64 VALU = 2cy/instr, so per-lane instruction count IS the time; this
// halves the fixed tax: butterfly 2 steps -> 1, prologue/epilogue amortized
// over 2 nodes. exp-dedup broadcast via quad ds_swizzle with LITERAL imm
// patterns (R3 fix: builtin requires integer-constant pattern). Garbage tail
// slots: cndmask to self (valid id) instead of 2-op clamp.
// FINAL=0: +bias, ELU, bf16 out. FINAL=1: +bias, fp32 out. No atomics.
// ---------------------------------------------------------------------------
template<int H, int FINAL>
__global__ __launch_bounds__(256) void aggregate(const int* __restrict__ cnt,
                                                 const int* __restrict__ csrc,
                                                 const unsigned short* __restrict__ h,
                                                 const float* __restrict__ als,
                                                 const float* __restrict__ ald,
                                                 const float* __restrict__ bias,
                                                 void* __restrict__ out) {
    const int wv = (int)((blockIdx.x * 256 + threadIdx.x) >> 6);   // wave id
    const int lane = threadIdx.x & 63;
    const int d = wv * 2 + (lane >> 5);        // 25000 waves cover 50000 nodes exactly
    const int hl = lane & 31;
    const int g2 = hl >> 4;                    // edge group within node: 0/1
    const int c0 = (hl & 15) * 8;              // this lane's 8 channels
    const int hd = (H == 4) ? (c0 >> 5) : 0;   // == (lane>>2)&3 when H==4
    const float aldd = (H == 4) ? ald[(size_t)d * 4 + hd] : ald[d];

    const char* hB   = (const char*)h;
    const char* alsB = (const char*)als;
    const char* csB  = (const char*)csrc;
    const unsigned coff = (unsigned)(c0 << 1);           // byte offset of my 8ch
    const unsigned aoff = (H == 4) ? (unsigned)(hd << 2) : 0u;
    const int myk = lane & 3;                            // the edge I exp for

    f32x2 acc2[4];
#pragma unroll
    for (int i = 0; i < 4; ++i) { acc2[i].x = 0.f; acc2[i].y = 0.f; }
    float den = 0.f;

    auto expw = [&](float av) {
        float v = av + aldd;
        v = fmaxf(v, 0.2f * v);        // leaky_relu, slope<1
        return __expf(fminf(v, 60.f));
    };
    auto accum = [&](uint4 hv, float ex) {
        f32x2 exv; exv.x = ex; exv.y = ex;
#pragma unroll
        for (int i = 0; i < 4; ++i) {
            unsigned w = ((const unsigned*)&hv)[i];
            f32x2 hf;
            hf.x = __uint_as_float(w << 16);
            hf.y = __uint_as_float(w & 0xffff0000u);
            acc2[i] += exv * hf;       // ch 2i (lo), 2i+1 (hi)
        }
        den += ex;
    };

    if (g2 == 0) {   // self-loop handled by group 0 of each half
        float av = (H == 4) ? als[(size_t)d * 4 + hd] : als[d];
        uint4 hv = *(const uint4*)(hB + (((unsigned)d << 8) + coff));
        accum(hv, expw(av));
    }

    const unsigned cbase = (unsigned)d << 8;             // bucket byte base
    const int c = min(cnt[d], CAP);
    for (int j0 = 0; j0 < c; j0 += 8) {
        int jb = j0 + 4 * g2;                            // my group's quad base
        int4 iv = *(const int4*)(csB + (cbase + ((unsigned)jb << 2)));
        bool p[4]; int idm[4];
#pragma unroll
        for (int k = 0; k < 4; ++k) {
            p[k] = (jb + k < c);
            idm[k] = p[k] ? ((const int*)&iv)[k] : d;    // tail: self (valid id)
        }
        uint4 hv[4];
#pragma unroll
        for (int k = 0; k < 4; ++k)
            hv[k] = *(const uint4*)(hB + (((unsigned)idm[k] << 8) + coff));
        // one als load + one exp per lane: my (edge=myk, head=hd)
        float avm = (H == 4) ? *(const float*)(alsB + (((unsigned)idm[myk] << 4) + aoff))
                             : *(const float*)(alsB + ((unsigned)idm[myk] << 2));
        float em = expw(avm);
        int emi = __float_as_int(em);
        // quad broadcast (literal imm patterns — builtin needs constants)
        int eb0 = __builtin_amdgcn_ds_swizzle(emi, 0x8000);
        int eb1 = __builtin_amdgcn_ds_swizzle(emi, 0x8055);
        int eb2 = __builtin_amdgcn_ds_swizzle(emi, 0x80AA);
        int eb3 = __builtin_amdgcn_ds_swizzle(emi, 0x80FF);
        accum(hv[0], p[0] ? __int_as_float(eb0) : 0.f);
        accum(hv[1], p[1] ? __int_as_float(eb1) : 0.f);
        accum(hv[2], p[2] ? __int_as_float(eb2) : 0.f);
        accum(hv[3], p[3] ? __int_as_float(eb3) : 0.f);
    }

    // combine the 2 groups of each node: butterfly over lane 16
#pragma unroll
    for (int i = 0; i < 4; ++i) {
        acc2[i].x += __shfl_xor(acc2[i].x, 16);
        acc2[i].y += __shfl_xor(acc2[i].y, 16);
    }
    den += __shfl_xor(den, 16);
    if (g2 != 0) return;   // lanes hl<16 of each half write their node

    const float inv = 1.f / den;
    float4 b0 = *(const float4*)&bias[c0];
    float4 b1 = *(const float4*)&bias[c0 + 4];
    float v[8];
    v[0] = acc2[0].x * inv + b0.x; v[1] = acc2[0].y * inv + b0.y;
    v[2] = acc2[1].x * inv + b0.z; v[3] = acc2[1].y * inv + b0.w;
    v[4] = acc2[2].x * inv + b1.x; v[5] = acc2[2].y * inv + b1.y;
    v[6] = acc2[3].x * inv + b1.z; v[7] = acc2[3].y * inv + b1.w;
    if (FINAL) {
        float* op = (float*)out + (size_t)d * 128 + c0;
        *(float4*)op       = make_float4(v[0], v[1], v[2], v[3]);
        *(float4*)(op + 4) = make_float4(v[4], v[5], v[6], v[7]);
    } else {
#pragma unroll
        for (int i = 0; i < 8; ++i) v[i] = v[i] > 0.f ? v[i] : expm1f(v[i]);
        unsigned int pk[4];
#pragma unroll
        for (int i = 0; i < 4; ++i)
            pk[i] = (unsigned int)f2bf_u(v[2 * i]) | ((unsigned int)f2bf_u(v[2 * i + 1]) << 16);
        *(uint4*)((unsigned short*)out + (size_t)d * 128 + c0) =
            make_uint4(pk[0], pk[1], pk[2], pk[3]);
    }
}

// ---------------------------------------------------------------------------
extern "C" void kernel_launch(void* const* d_in, const int* in_sizes, int n_in,
                              void* d_out, int out_size, void* d_ws, size_t ws_size,
                              hipStream_t stream) {
    const float* x      = (const float*)d_in[0];
    const int*   ei     = (const int*)d_in[1];
    const float* W1     = (const float*)d_in[2];
    const float* a_src1 = (const float*)d_in[3];
    const float* a_dst1 = (const float*)d_in[4];
    const float* b1     = (const float*)d_in[5];
    const float* W2     = (const float*)d_in[6];
    const float* a_src2 = (const float*)d_in[7];
    const float* a_dst2 = (const float*)d_in[8];
    const float* b2     = (const float*)d_in[9];

    const int N = NN;

    // Workspace: explicit BYTE offsets, every buffer 16B-aligned.
    char* base = (char*)d_ws;
    int*   cnt  = (int*)(base + 0);                       //  50000 i
    int*   csrc = (int*)(base + 200000);                  //  50000*64 i (bucketed)
    float* als  = (float*)(base + 13000000);              // 200000 f
    float* ald  = (float*)(base + 13800000);              // 200000 f
    unsigned short* h   = (unsigned short*)(base + 14600000);  // N*128 bf16
    unsigned short* x2  = (unsigned short*)(base + 27400000);  // N*128 bf16
    unsigned short* wt1 = (unsigned short*)(base + 40200000);  // 16384 bf16
    unsigned short* wt2 = (unsigned short*)(base + 40232768);  // 16384 bf16
    // total ~40.27 MB

    const int gemmGrid  = (N + 63) / 64;          // 782
    const int edgeGrid  = (NE + 255) / 256;       // 2344
    const int zeroGrid  = (N + 255) / 256;        // 196
    const int aggGrid   = N / 8;                  // 6250 (2 nodes/wave, 4 waves/block)

    prep_zero<<<128 + zeroGrid, 256, 0, stream>>>(W1, W2, wt1, wt2, cnt);
    csr_fill<<<edgeGrid, 256, 0, stream>>>(ei, cnt, csrc);
    gemm_fused<4, 1><<<gemmGrid, 256, 0, stream>>>(x, wt1, a_src1, a_dst1, h, als, ald, N);
    aggregate<4, 0><<<aggGrid, 256, 0, stream>>>(cnt, csrc, h, als, ald, b1, x2);
    gemm_fused<1, 0><<<gemmGrid, 256, 0, stream>>>(x2, wt2, a_src2, a_dst2, h, als, ald, N);
    aggregate<1, 1><<<aggGrid, 256, 0, stream>>>(cnt, csrc, h, als, ald, b2, d_out);
}